// Round 9
// baseline (167.910 us; speedup 1.0000x reference)
//
#include <hip/hip_runtime.h>
#include <math.h>

typedef unsigned short ushort_t;
typedef __attribute__((ext_vector_type(4))) float f32x4;
typedef __attribute__((ext_vector_type(16))) float f32x16;
typedef __attribute__((ext_vector_type(8))) short bf16x8;

constexpr int B = 8, C = 128, H = 64, W = 64;
constexpr int HEADS = 8, TOPK = 16;
constexpr int P2 = 64;
constexpr float SCALE = 0.0883883476483184405f; // 128^-0.5

// workspace offsets (in floats)
constexpr size_t NPIX    = (size_t)B * H * W;            // 32768
constexpr size_t OFF_T1C = 0;                            // NHWC fp32; later: o bf16
constexpr size_t OFF_T2C = OFF_T1C + NPIX * 128;         // NHWC fp32; later: v planes bf16
constexpr size_t OFF_X   = OFF_T2C + NPIX * 128;         // xbuf bf16 [pix][128]
constexpr size_t OFF_QB  = OFF_X   + NPIX * 128;         // q*SCALE bf16
constexpr size_t OFF_KV  = OFF_QB  + NPIX * 64;          // kv bf16 [pix][256]; later: lep planes bf16
constexpr size_t OFF_KVP = OFF_KV  + NPIX * 256;         // K bf16 [B,64,16,128]
constexpr size_t OFF_RW1 = OFF_KVP + 524288;             // rowsums q  [B][8][64][128] fp32
constexpr size_t OFF_RW2 = OFF_RW1 + 524288;             // rowsums kv [B][8][64][128] fp32
constexpr size_t OFF_KVPT= OFF_KVP + (size_t)B * P2 * 16 * 256; // v^T bf16 [B,64,128,16]
constexpr size_t OFF_QW  = OFF_KVPT+ (size_t)B * P2 * 128 * 16 / 2;
constexpr size_t OFF_KW  = OFF_QW  + (size_t)B * P2 * 128;
constexpr size_t OFF_RIDX= OFF_KW  + (size_t)B * P2 * 128;      // int
constexpr size_t OFF_WCB = OFF_RIDX+ (size_t)B * P2 * TOPK;     // wcat2 bf16 [36][2][4][128][8]
constexpr size_t OFF_QKVB= OFF_WCB + (size_t)9 * 256 * 128;     // qkv_w bf16 [384][128]
constexpr size_t OFF_WOB = OFF_QKVB+ (size_t)384 * 128 / 2;     // wo bf16 [128][128]
constexpr size_t OFF_T1B = OFF_WOB + 8192;               // t1 NHWC bf16 [pix][128]
constexpr size_t OFF_T2B = OFF_T1B + NPIX * 64;          // t2 NHWC bf16 [pix][128]

__device__ inline ushort_t f2bf(float f) {
    unsigned u = __float_as_uint(f);
    unsigned r = u + 0x7FFFu + ((u >> 16) & 1u);
    return (ushort_t)(r >> 16);
}
__device__ inline float bf2f(ushort_t u) {
    return __uint_as_float((unsigned)u << 16);
}

// ---------------------------------------------------------------- weights prep
__global__ void transpose_weights(const float* __restrict__ qkv_w,
                                  const float* __restrict__ wo_w,
                                  const float* __restrict__ cat_w,
                                  ushort_t* __restrict__ qkvB,
                                  ushort_t* __restrict__ woB,
                                  ushort_t* __restrict__ wcat2) {
    int idx = blockIdx.x * 256 + threadIdx.x;
    if (idx < 384 * 128) qkvB[idx] = f2bf(qkv_w[idx]);   // [n][k]
    if (idx < 128 * 128) woB[idx]  = f2bf(wo_w[idx]);    // [n][k]
    if (idx < 36 * 8 * 128 * 8) {    // wcat2[((q*9+dd)*8+kk*4+lg)][n][i]
        int i  = idx & 7;
        int n  = (idx >> 3) & 127;
        int r  = idx >> 10;
        int lg = r & 3;
        int kk = (r >> 2) & 1;
        int sdd = r >> 3;
        int dd = sdd % 9, q = sdd / 9;
        int ci = q * 64 + kk * 32 + lg * 8 + i;
        wcat2[idx] = f2bf(cat_w[((size_t)n * 256 + ci) * 9 + dd]);
    }
}

// ---- depthwise 3x3 + residual, NCHW->NHWC fp32 + bf16 copy; both tensors
__global__ __launch_bounds__(256) void pos_conv_k(
        const float* __restrict__ t1, const float* __restrict__ t2,
        const float* __restrict__ w, const float* __restrict__ bias,
        float* __restrict__ out1, float* __restrict__ out2,
        ushort_t* __restrict__ ob1, ushort_t* __restrict__ ob2) {
    __shared__ float tile[4][32][33];
    int z = blockIdx.z;
    int which = z >> 7, rem = z & 127;
    int b = rem >> 4, y0 = (rem & 15) * 4;
    const float* in = which ? t2 : t1;
    float* outNHWC = which ? out2 : out1;
    ushort_t* outB = which ? ob2 : ob1;
    int c0 = blockIdx.y * 32, x0 = blockIdx.x * 32;
    int tx = threadIdx.x & 31, tg = threadIdx.x >> 5;
    int x = x0 + tx;
    for (int i = 0; i < 4; i++) {
        int cl = tg * 4 + i, c = c0 + cl;
        const float* base = in + (size_t)(b * C + c) * H * W;
        float wv[9];
#pragma unroll
        for (int j = 0; j < 9; j++) wv[j] = w[c * 9 + j];
        float rows[6][3];
#pragma unroll
        for (int yy = 0; yy < 6; yy++) {
            int gy = y0 - 1 + yy;
            bool yok = (gy >= 0 && gy < H);
#pragma unroll
            for (int dx = 0; dx < 3; dx++) {
                int gx = x + dx - 1;
                rows[yy][dx] = (yok && gx >= 0 && gx < W) ? base[gy * W + gx] : 0.f;
            }
        }
        float bb = bias[c];
#pragma unroll
        for (int k = 0; k < 4; k++) {
            float acc = rows[k + 1][1] + bb;   // residual (center) + bias
#pragma unroll
            for (int dy = 0; dy < 3; dy++)
#pragma unroll
                for (int dx = 0; dx < 3; dx++)
                    acc += rows[k + dy][dx] * wv[dy * 3 + dx];
            tile[k][cl][tx] = acc;
        }
    }
    __syncthreads();
    for (int k = 0; k < 4; k++)
        for (int i = 0; i < 4; i++) {
            int xl = tg * 4 + i;
            float val = tile[k][tx][xl];
            size_t idx = ((size_t)(b * H + y0 + k) * W + x0 + xl) * 128 + c0 + tx;
            outNHWC[idx] = val;
            outB[idx] = f2bf(val);
        }
}

// ------------- cat-conv 256->128 3x3 implicit-GEMM MFMA + fused LN+ReLU
// stages from pre-converted bf16 NHWC copies (pure copy, no conversion)
__global__ __launch_bounds__(512) void catconv_mfma_k(
        const ushort_t* __restrict__ t1b, const ushort_t* __restrict__ t2b,
        const ushort_t* __restrict__ wcat2,
        const float* __restrict__ cat_b,
        const float* __restrict__ g, const float* __restrict__ beta,
        ushort_t* __restrict__ xbuf) {
    __shared__ __align__(16) unsigned char smem[64 * 132 * 4 + 2 * 64 * 4];
    int t = threadIdx.x;
    int lane = t & 63, wv = t >> 6;
    int mw = wv >> 2, nw = wv & 3;
    int l15 = lane & 15, lg = lane >> 4;
    int b = blockIdx.z, y0 = blockIdx.y * 8, x0 = blockIdx.x * 8;

    f32x4 acc[2][2];
#pragma unroll
    for (int m = 0; m < 2; m++)
#pragma unroll
        for (int cf = 0; cf < 2; cf++)
            acc[m][cf] = (f32x4){0.f, 0.f, 0.f, 0.f};

    int pyA[2], pxA[2];
#pragma unroll
    for (int m = 0; m < 2; m++) {
        int p = mw * 32 + m * 16 + l15;
        pyA[m] = p >> 3; pxA[m] = p & 7;
    }

    for (int q = 0; q < 4; q++) {
        __syncthreads();
        {
            const ushort_t* src = (q < 2 ? t1b : t2b);
            int coff = (q & 1) * 64;
            for (int e = t; e < 800; e += 512) {
                int pix = e >> 3, c8 = e & 7;
                int hy = pix / 10, hx = pix - hy * 10;
                int gy = y0 - 1 + hy, gx = x0 - 1 + hx;
                uint4 v = make_uint4(0u, 0u, 0u, 0u);
                if (gy >= 0 && gy < H && gx >= 0 && gx < W)
                    v = *reinterpret_cast<const uint4*>(
                        src + ((size_t)(b * H + gy) * W + gx) * 128 + coff + c8 * 8);
                *reinterpret_cast<uint4*>(smem + pix * 144 + c8 * 16) = v;
            }
        }
        __syncthreads();
#pragma unroll
        for (int dd = 0; dd < 9; dd++) {
            int dy = dd / 3, dx = dd - dy * 3;
            const ushort_t* wb = wcat2 + ((size_t)((q * 9 + dd) * 8 + lg) * 128) * 8;
            bf16x8 bfr[2][2];
#pragma unroll
            for (int kk = 0; kk < 2; kk++)
#pragma unroll
                for (int cf = 0; cf < 2; cf++)
                    bfr[kk][cf] = *reinterpret_cast<const bf16x8*>(
                        wb + (size_t)kk * 4096 + (nw * 32 + cf * 16 + l15) * 8);
            bf16x8 af[2][2];
#pragma unroll
            for (int m = 0; m < 2; m++)
#pragma unroll
                for (int kk = 0; kk < 2; kk++)
                    af[m][kk] = *reinterpret_cast<const bf16x8*>(
                        smem + ((pyA[m] + dy) * 10 + pxA[m] + dx) * 144 + kk * 64 + lg * 16);
#pragma unroll
            for (int m = 0; m < 2; m++)
#pragma unroll
                for (int cf = 0; cf < 2; cf++)
#pragma unroll
                    for (int kk = 0; kk < 2; kk++)
                        acc[m][cf] = __builtin_amdgcn_mfma_f32_16x16x32_bf16(
                            af[m][kk], bfr[kk][cf], acc[m][cf], 0, 0, 0);
        }
    }

    __syncthreads();
    float* res = (float*)smem;
    float* mstat = (float*)(smem + 64 * 132 * 4);
#pragma unroll
    for (int cf = 0; cf < 2; cf++) {
        int n = nw * 32 + cf * 16 + l15;
        float cb = cat_b[n];
#pragma unroll
        for (int m = 0; m < 2; m++)
#pragma unroll
            for (int i = 0; i < 4; i++)
                res[(mw * 32 + m * 16 + lg * 4 + i) * 132 + n] = acc[m][cf][i] + cb;
    }
    __syncthreads();
    {
        int pix = t >> 3, sub = t & 7;
        float s1 = 0.f;
#pragma unroll
        for (int j = 0; j < 16; j++) s1 += res[pix * 132 + sub + j * 8];
        s1 += __shfl_xor(s1, 1, 64);
        s1 += __shfl_xor(s1, 2, 64);
        s1 += __shfl_xor(s1, 4, 64);
        float mean = s1 * (1.f / 128.f);
        float s2 = 0.f;
#pragma unroll
        for (int j = 0; j < 16; j++) {
            float d = res[pix * 132 + sub + j * 8] - mean;
            s2 += d * d;
        }
        s2 += __shfl_xor(s2, 1, 64);
        s2 += __shfl_xor(s2, 2, 64);
        s2 += __shfl_xor(s2, 4, 64);
        float inv = rsqrtf(s2 * (1.f / 128.f) + 1e-5f);
        if (sub == 0) { mstat[pix] = mean; mstat[64 + pix] = inv; }
    }
    __syncthreads();
    {
        int c = t & 127, pg = t >> 7;
        float gg = g[c], bb = beta[c];
        for (int j = 0; j < 16; j++) {
            int p2 = j * 4 + pg;
            float v = (res[p2 * 132 + c] - mstat[p2]) * mstat[64 + p2] * gg + bb;
            int py = p2 >> 3, px = p2 & 7;
            xbuf[((size_t)(b * H + y0 + py) * W + x0 + px) * 128 + c] = f2bf(fmaxf(v, 0.f));
        }
    }
}

// ---- LN(1e-6) + QKV projection (both streams in one kernel) + window rowsums
__global__ __launch_bounds__(256) void ln_qkv_both_k(
        const float* __restrict__ t1c, const float* __restrict__ t2c,
        const float* __restrict__ g, const float* __restrict__ beta,
        const ushort_t* __restrict__ wB,   // bf16 [384][128]
        const float* __restrict__ bias,
        ushort_t* __restrict__ outQ,
        ushort_t* __restrict__ outKV,
        float* __restrict__ rw1, float* __restrict__ rw2) {
    __shared__ __align__(16) unsigned char ash[64 * 272];
    int t = threadIdx.x;
    int lane = t & 63, wv = t >> 6;
    int which = blockIdx.y;
    const float* in = which ? t2c : t1c;
    float* rw = which ? rw2 : rw1;
    size_t p0 = (size_t)blockIdx.x * 64;
    int bb_ = blockIdx.x >> 6, yy_ = blockIdx.x & 63;
    {
        int row = t >> 2, sub = t & 3;     // row = x coordinate
        const float* src = in + (p0 + row) * 128 + sub * 32;
        float4 v[8];
        float s = 0.f;
#pragma unroll
        for (int j = 0; j < 8; j++) {
            v[j] = *reinterpret_cast<const float4*>(src + j * 4);
            s += v[j].x + v[j].y + v[j].z + v[j].w;
        }
        s += __shfl_xor(s, 1, 64); s += __shfl_xor(s, 2, 64);
        float mean = s * (1.f / 128.f);
        float s2 = 0.f;
#pragma unroll
        for (int j = 0; j < 8; j++) {
            float dx = v[j].x - mean, dy = v[j].y - mean;
            float dz = v[j].z - mean, dw = v[j].w - mean;
            s2 += dx * dx + dy * dy + dz * dz + dw * dw;
        }
        s2 += __shfl_xor(s2, 1, 64); s2 += __shfl_xor(s2, 2, 64);
        float inv = rsqrtf(s2 * (1.f / 128.f) + 1e-6f);
        int wj = wv * 2 + (lane >> 5);
        bool writer = (lane & 28) == 0;
        float* rwp = rw + (((size_t)(bb_ * 8 + wj) * 64 + yy_) * 128) + sub * 32;
#pragma unroll
        for (int j = 0; j < 8; j++) {
            int c = sub * 32 + j * 4;
            float4 gv = *reinterpret_cast<const float4*>(g + c);
            float4 bv = *reinterpret_cast<const float4*>(beta + c);
            float o0 = (v[j].x - mean) * inv * gv.x + bv.x;
            float o1 = (v[j].y - mean) * inv * gv.y + bv.y;
            float o2 = (v[j].z - mean) * inv * gv.z + bv.z;
            float o3 = (v[j].w - mean) * inv * gv.w + bv.w;
            uint2 pk;
            pk.x = (unsigned)f2bf(o0) | ((unsigned)f2bf(o1) << 16);
            pk.y = (unsigned)f2bf(o2) | ((unsigned)f2bf(o3) << 16);
            *reinterpret_cast<uint2*>(ash + row * 272 + c * 2) = pk;
            float r0 = o0, r1 = o1, r2 = o2, r3 = o3;
#pragma unroll
            for (int m = 4; m <= 16; m <<= 1) {
                r0 += __shfl_xor(r0, m, 64);
                r1 += __shfl_xor(r1, m, 64);
                r2 += __shfl_xor(r2, m, 64);
                r3 += __shfl_xor(r3, m, 64);
            }
            if (writer)
                *reinterpret_cast<float4*>(rwp + j * 4) = make_float4(r0, r1, r2, r3);
        }
    }
    __syncthreads();
    int l15 = lane & 15, lg = lane >> 4;
    if (which == 0) {
        f32x4 acc[4][2];
#pragma unroll
        for (int mt = 0; mt < 4; mt++)
#pragma unroll
            for (int nn = 0; nn < 2; nn++)
                acc[mt][nn] = (f32x4){0.f, 0.f, 0.f, 0.f};
#pragma unroll
        for (int ks = 0; ks < 4; ks++) {
            bf16x8 af[4];
#pragma unroll
            for (int mt = 0; mt < 4; mt++)
                af[mt] = *reinterpret_cast<const bf16x8*>(
                    ash + (mt * 16 + l15) * 272 + ks * 64 + lg * 16);
#pragma unroll
            for (int nn = 0; nn < 2; nn++) {
                int n = (wv * 2 + nn) * 16 + l15;
                bf16x8 bfr = *reinterpret_cast<const bf16x8*>(
                    wB + (size_t)n * 128 + ks * 32 + lg * 8);
#pragma unroll
                for (int mt = 0; mt < 4; mt++)
                    acc[mt][nn] = __builtin_amdgcn_mfma_f32_16x16x32_bf16(
                        af[mt], bfr, acc[mt][nn], 0, 0, 0);
            }
        }
#pragma unroll
        for (int nn = 0; nn < 2; nn++) {
            int cg = (wv * 2 + nn) * 16 + l15;
            float bv = bias[cg];
#pragma unroll
            for (int mt = 0; mt < 4; mt++)
#pragma unroll
                for (int i = 0; i < 4; i++) {
                    size_t pix = p0 + mt * 16 + lg * 4 + i;
                    outQ[pix * 128 + cg] = f2bf((acc[mt][nn][i] + bv) * SCALE);
                }
        }
    } else {
        f32x4 acc[4][4];
#pragma unroll
        for (int mt = 0; mt < 4; mt++)
#pragma unroll
            for (int nn = 0; nn < 4; nn++)
                acc[mt][nn] = (f32x4){0.f, 0.f, 0.f, 0.f};
#pragma unroll
        for (int ks = 0; ks < 4; ks++) {
            bf16x8 af[4];
#pragma unroll
            for (int mt = 0; mt < 4; mt++)
                af[mt] = *reinterpret_cast<const bf16x8*>(
                    ash + (mt * 16 + l15) * 272 + ks * 64 + lg * 16);
#pragma unroll
            for (int nn = 0; nn < 4; nn++) {
                int n = 128 + (wv * 4 + nn) * 16 + l15;
                bf16x8 bfr = *reinterpret_cast<const bf16x8*>(
                    wB + (size_t)n * 128 + ks * 32 + lg * 8);
#pragma unroll
                for (int mt = 0; mt < 4; mt++)
                    acc[mt][nn] = __builtin_amdgcn_mfma_f32_16x16x32_bf16(
                        af[mt], bfr, acc[mt][nn], 0, 0, 0);
            }
        }
#pragma unroll
        for (int nn = 0; nn < 4; nn++) {
            int cg = (wv * 4 + nn) * 16 + l15;
            float bv = bias[128 + cg];
#pragma unroll
            for (int mt = 0; mt < 4; mt++)
#pragma unroll
                for (int i = 0; i < 4; i++) {
                    size_t pix = p0 + mt * 16 + lg * 4 + i;
                    outKV[pix * 256 + cg] = f2bf(acc[mt][nn][i] + bv);
                }
        }
    }
}

// -------- fp32 q_win/k_win projection; reduces rowsums (8 rows/window) on load
__global__ __launch_bounds__(256) void route_gemm_k(
        const float* __restrict__ rw1, const float* __restrict__ rw2,
        const float* __restrict__ qkv_w, const float* __restrict__ qkv_b,
        float* __restrict__ qwin, float* __restrict__ kwin) {
    __shared__ float msh[2][8][128];
    int b = blockIdx.y, wi = blockIdx.x;   // windows win = wi*8 + r
    int t = threadIdx.x;
    for (int i = t; i < 8 * 128; i += 256) {
        int r = i >> 7, c = i & 127;
        size_t off = (((size_t)(b * 8 + r) * 64) + wi * 8) * 128 + c;
        float s1 = 0.f, s2 = 0.f;
#pragma unroll
        for (int rr = 0; rr < 8; rr++) {
            s1 += rw1[off + rr * 128];
            s2 += rw2[off + rr * 128];
        }
        msh[0][r][c] = s1 * (1.f / 64.f);
        msh[1][r][c] = s2 * (1.f / 64.f);
    }
    __syncthreads();
    int c = t;
    int which = c >> 7;
    const float* wrow = qkv_w + (size_t)c * 128;
    float acc[8];
#pragma unroll
    for (int r = 0; r < 8; r++) acc[r] = 0.f;
    for (int k = 0; k < 128; k++) {
        float wv_ = wrow[k];
#pragma unroll
        for (int r = 0; r < 8; r++) acc[r] += msh[which][r][k] * wv_;
    }
    float bv = qkv_b[c];
#pragma unroll
    for (int r = 0; r < 8; r++) {
        size_t o = ((size_t)b * 64 + wi * 8 + r) * 128 + (c & 127);
        (which ? kwin : qwin)[o] = acc[r] + bv;
    }
}

// ------------------------------------------------ routing logits + top-16
__global__ __launch_bounds__(64) void route_k(const float* __restrict__ q_win,
                                              const float* __restrict__ k_win,
                                              int* __restrict__ r_idx) {
    int b = blockIdx.y, p = blockIdx.x, j = threadIdx.x;
    const float* qp = q_win + (size_t)(b * 64 + p) * 128;
    const float* kp = k_win + (size_t)(b * 64 + j) * 128;
    float lg = 0.f;
    for (int c = 0; c < 128; c++) lg += qp[c] * kp[c];
    lg *= SCALE;
    for (int it = 0; it < TOPK; it++) {
        float v = lg; int idx = j;
#pragma unroll
        for (int m = 32; m > 0; m >>= 1) {
            float ov = __shfl_xor(v, m, 64);
            int   oi = __shfl_xor(idx, m, 64);
            if (ov > v || (ov == v && oi < idx)) { v = ov; idx = oi; }
        }
        if (j == 0) r_idx[(size_t)(b * 64 + p) * TOPK + it] = idx;
        if (j == idx) lg = -__builtin_inff();
    }
}

// -------- pooling (K bf16 + v^T bf16) fused with v-plane transpose (vpl bf16)
__global__ __launch_bounds__(256) void pool_v_k(const ushort_t* __restrict__ kv,
                                                ushort_t* __restrict__ kb,
                                                ushort_t* __restrict__ kvpT,
                                                ushort_t* __restrict__ vpl) {
    int b = blockIdx.y, wdw = blockIdx.x;
    int wi = wdw >> 3, wj = wdw & 7;
    int t = threadIdx.x;
    if (t < 128) {
        float vals[16];
        for (int ry = 0; ry < 4; ry++)
            for (int rx = 0; rx < 4; rx++) {
                float s = 0.f;
                for (int fy = 0; fy < 2; fy++)
                    for (int fx = 0; fx < 2; fx++) {
                        int y = wi * 8 + ry * 2 + fy, x = wj * 8 + rx * 2 + fx;
                        s += bf2f(kv[((size_t)(b * H + y) * W + x) * 256 + t]);
                    }
                vals[ry * 4 + rx] = s * 0.25f;
            }
#pragma unroll
        for (int pos = 0; pos < 16; pos++)
            kb[(((size_t)(b * 64 + wdw)) * 16 + pos) * 128 + t] = f2bf(vals[pos]);
    } else {
        int c = t - 128;
        float ps[4][4];
#pragma unroll
        for (int i = 0; i < 4; i++)
#pragma unroll
            for (int j = 0; j < 4; j++) ps[i][j] = 0.f;
        for (int y = 0; y < 8; y++) {
            union { ushort_t u16[8]; uint4 u4; } raw;
#pragma unroll
            for (int x = 0; x < 8; x++) {
                raw.u16[x] = kv[((size_t)(b * H + wi * 8 + y) * W + wj * 8 + x) * 256 + 128 + c];
                ps[y >> 1][x >> 1] += bf2f(raw.u16[x]);
            }
            *reinterpret_cast<uint4*>(
                vpl + ((size_t)(b * C + c) * H + wi * 8 + y) * W + wj * 8) = raw.u4;
        }
        union { ushort_t u16[16]; uint4 u4[2]; } pk;
#pragma unroll
        for (int ry = 0; ry < 4; ry++)
#pragma unroll
            for (int rx = 0; rx < 4; rx++)
                pk.u16[ry * 4 + rx] = f2bf(ps[ry][rx] * 0.25f);
        size_t base = (((size_t)(b * 64 + wdw)) * 128 + c) * 16;
        *reinterpret_cast<uint4*>(kvpT + base) = pk.u4[0];
        *reinterpret_cast<uint4*>(kvpT + base + 8) = pk.u4[1];
    }
}

// ---------------- routed attention: staging-free; LDS-restaged coalesced output
__global__ __launch_bounds__(256) void attn_mfma_k(
        const ushort_t* __restrict__ qb,     // bf16 q*SCALE [B,H,W,128]
        const ushort_t* __restrict__ kb,     // bf16 [B,64,16,128]
        const ushort_t* __restrict__ kvpT,   // bf16 [B,64,128,16]
        const int* __restrict__ r_idx,
        ushort_t* __restrict__ o) {          // bf16 [pix][128]
    __shared__ int ridx_sh[16];
    __shared__ float denom_sh[4][32];
    __shared__ __align__(16) ushort_t osh[64][32];

    int b = blockIdx.z, p = blockIdx.x, pair = blockIdx.y;
    int wi = p >> 3, wj = p & 7;
    int t = threadIdx.x;
    int lane = t & 63, wv = t >> 6;
    int l31 = lane & 31, hi = lane >> 5;

    if (t < 16) ridx_sh[t] = r_idx[(size_t)(b * 64 + p) * TOPK + t];
    __syncthreads();

    int hh = wv >> 1, qt = wv & 1;
    int h = pair * 2 + hh;

    int q = qt * 32 + l31;
    int qy = wi * 8 + (q >> 3), qx = wj * 8 + (q & 7);
    bf16x8 qf = *reinterpret_cast<const bf16x8*>(
        qb + ((size_t)(b * H + qy) * W + qx) * 128 + h * 16 + hi * 8);

    const ushort_t* kb_b = kb + (size_t)b * 64 * 16 * 128 + h * 16 + hi * 8;
    const ushort_t* vt_b = kvpT + (size_t)b * 64 * 128 * 16 + (h * 16 + (l31 & 15)) * 16 + hi * 8;

    float m_run = -INFINITY, l_run = 0.f;
    f32x16 opv;
#pragma unroll
    for (int r = 0; r < 16; r++) opv[r] = 0.f;
    f32x16 zf;
#pragma unroll
    for (int r = 0; r < 16; r++) zf[r] = 0.f;

    bf16x8 kf = *reinterpret_cast<const bf16x8*>(
        kb_b + ((size_t)ridx_sh[l31 >> 4] * 16 + (l31 & 15)) * 128);
    bf16x8 v0 = *reinterpret_cast<const bf16x8*>(vt_b + (size_t)ridx_sh[0] * 2048);
    bf16x8 v1 = *reinterpret_cast<const bf16x8*>(vt_b + (size_t)ridx_sh[1] * 2048);

    for (int t8 = 0; t8 < 8; t8++) {
        bf16x8 kfn = kf, v0n = v0, v1n = v1;
        if (t8 < 7) {
            kfn = *reinterpret_cast<const bf16x8*>(
                kb_b + ((size_t)ridx_sh[2 * t8 + 2 + (l31 >> 4)] * 16 + (l31 & 15)) * 128);
            v0n = *reinterpret_cast<const bf16x8*>(vt_b + (size_t)ridx_sh[2 * t8 + 2] * 2048);
            v1n = *reinterpret_cast<const bf16x8*>(vt_b + (size_t)ridx_sh[2 * t8 + 3] * 2048);
        }
        f32x16 S = __builtin_amdgcn_mfma_f32_32x32x16_bf16(kf, qf, zf, 0, 0, 0);
        float tm = S[0];
#pragma unroll
        for (int r = 1; r < 16; r++) tm = fmaxf(tm, S[r]);
        tm = fmaxf(tm, __shfl_xor(tm, 32, 64));
        float m_new = fmaxf(m_run, tm);
        float corr = __expf(m_run - m_new);
        float p_[16], psum = 0.f;
#pragma unroll
        for (int r = 0; r < 16; r++) { p_[r] = __expf(S[r] - m_new); psum += p_[r]; }
        psum += __shfl_xor(psum, 32, 64);
        l_run = l_run * corr + psum;
        m_run = m_new;
#pragma unroll
        for (int r = 0; r < 16; r++) opv[r] *= corr;
        unsigned w_[8], pw_[8];
#pragma unroll
        for (int j = 0; j < 8; j++)
            w_[j] = (__float_as_uint(p_[2 * j]) >> 16) |
                    (__float_as_uint(p_[2 * j + 1]) & 0xFFFF0000u);
#pragma unroll
        for (int j = 0; j < 8; j++) pw_[j] = __shfl_xor(w_[j], 32, 64);
        union { unsigned u[4]; bf16x8 v; } fa0, fa1;
        fa0.u[0] = hi ? pw_[2] : w_[0];
        fa0.u[1] = hi ? pw_[3] : w_[1];
        fa0.u[2] = hi ? w_[2]  : pw_[0];
        fa0.u[3] = hi ? w_[3]  : pw_[1];
        fa1.u[0] = hi ? pw_[6] : w_[4];
        fa1.u[1] = hi ? pw_[7] : w_[5];
        fa1.u[2] = hi ? w_[6]  : pw_[4];
        fa1.u[3] = hi ? w_[7]  : pw_[5];
        opv = __builtin_amdgcn_mfma_f32_32x32x16_bf16(fa0.v, v0, opv, 0, 0, 0);
        opv = __builtin_amdgcn_mfma_f32_32x32x16_bf16(fa1.v, v1, opv, 0, 0, 0);
        kf = kfn; v0 = v0n; v1 = v1n;
    }
    denom_sh[wv][l31] = l_run;
    if (l31 < 16) {
#pragma unroll
        for (int r = 0; r < 16; r++) {
            int qr = (r & 3) + 8 * (r >> 2) + 4 * hi;
            float invd = 1.f / denom_sh[wv][qr];
            osh[qt * 32 + qr][hh * 16 + l31] = f2bf(opv[r] * invd);
        }
    }
    __syncthreads();
    {
        int p_ = t >> 2, seg = t & 3;
        int y = wi * 8 + (p_ >> 3), x = wj * 8 + (p_ & 7);
        *reinterpret_cast<uint4*>(
            o + ((size_t)(b * H + y) * W + x) * 128 + pair * 32 + seg * 8) =
            *reinterpret_cast<const uint4*>(&osh[p_][seg * 8]);
    }
}

// ------------------ LePE depthwise 5x5 on bf16 planes, LDS-tiled, bf16 out
__global__ __launch_bounds__(256) void lepe_plane_k(const ushort_t* __restrict__ vpl,
                                                    const float* __restrict__ w,
                                                    const float* __restrict__ bias,
                                                    ushort_t* __restrict__ lep) {
    __shared__ float tile[68][69];
    int c = blockIdx.x, b = blockIdx.y;
    int t = threadIdx.x;
    const ushort_t* plane = vpl + (size_t)(b * C + c) * 4096;
    for (int e = t; e < 68 * 68; e += 256) {
        int row = e / 68, col = e - row * 68;
        int gy = row - 2, gx = col - 2;
        tile[row][col] = (gy >= 0 && gy < 64 && gx >= 0 && gx < 64)
                         ? bf2f(plane[gy * 64 + gx]) : 0.f;
    }
    float wv[25];
#pragma unroll
    for (int j = 0; j < 25; j++) wv[j] = w[c * 25 + j];
    float bb = bias[c];
    __syncthreads();
    int y = t >> 2, x0 = (t & 3) * 16;
    float acc[16];
#pragma unroll
    for (int i = 0; i < 16; i++) acc[i] = bb;
#pragma unroll
    for (int dy = 0; dy < 5; dy++) {
        float vals[20];
#pragma unroll
        for (int j = 0; j < 20; j++) vals[j] = tile[y + dy][x0 + j];
#pragma unroll
        for (int dx = 0; dx < 5; dx++)
#pragma unroll
            for (int i = 0; i < 16; i++)
                acc[i] += vals[i + dx] * wv[dy * 5 + dx];
    }
    ushort_t* dst = lep + (size_t)(b * C + c) * 4096 + y * 64 + x0;
    union { ushort_t u16[16]; uint4 u4[2]; } pk;
#pragma unroll
    for (int i = 0; i < 16; i++) pk.u16[i] = f2bf(acc[i]);
    *reinterpret_cast<uint4*>(dst) = pk.u4[0];
    *reinterpret_cast<uint4*>(dst + 8) = pk.u4[1];
}

// ---- epilogue: ((o + lepe) @ Wo^T + b) + x, bf16 MFMA, NCHW store via LDS
__global__ __launch_bounds__(256) void epilogue_mfma_k(
        const ushort_t* __restrict__ o,      // bf16 [pix][128]
        const ushort_t* __restrict__ lep,    // bf16 planes [B][C][64][64]
        const ushort_t* __restrict__ xbuf,   // bf16 [pix][128]
        const ushort_t* __restrict__ woB,    // bf16 [128][128]
        const float* __restrict__ wo_b,
        float* __restrict__ out) {
    __shared__ __align__(16) unsigned char smem[128 * 68 * 4]; // 34816 B
    ushort_t* ash = (ushort_t*)smem;         // [64][136] bf16 (o+lep)
    float* res = (float*)smem;               // [128][68] fp32 (after MFMA)
    int t = threadIdx.x, lane = t & 63, wv = t >> 6;
    int bid = blockIdx.x;
    int b = bid >> 6, y = bid & 63;
    size_t p0 = (size_t)bid * 64;

#pragma unroll
    for (int k = 0; k < 4; k++) {
        int e = k * 256 + t;
        int c = e >> 3, xg = e & 7;
        union { uint4 u4; ushort_t u16[8]; } v;
        v.u4 = *reinterpret_cast<const uint4*>(
            lep + (((size_t)(b * C + c) * 64 + y) * 64) + xg * 8);
#pragma unroll
        for (int j = 0; j < 8; j++) ash[(xg * 8 + j) * 136 + c] = v.u16[j];
    }
    __syncthreads();
    {
        int x = t >> 2, sub = t & 3;
        const ushort_t* op = o + (p0 + x) * 128 + sub * 32;
        ushort_t* ap = ash + x * 136 + sub * 32;
#pragma unroll
        for (int jj = 0; jj < 4; jj++) {
            union { uint4 u4; ushort_t u16[8]; } ov, lv;
            ov.u4 = *reinterpret_cast<const uint4*>(op + jj * 8);
            lv.u4 = *reinterpret_cast<const uint4*>(ap + jj * 8);
#pragma unroll
            for (int j = 0; j < 8; j++)
                lv.u16[j] = f2bf(bf2f(ov.u16[j]) + bf2f(lv.u16[j]));
            *reinterpret_cast<uint4*>(ap + jj * 8) = lv.u4;
        }
    }
    __syncthreads();
    int l15 = lane & 15, lg = lane >> 4;
    f32x4 acc[4][2];
#pragma unroll
    for (int mt = 0; mt < 4; mt++)
#pragma unroll
        for (int nn = 0; nn < 2; nn++)
            acc[mt][nn] = (f32x4){0.f, 0.f, 0.f, 0.f};
#pragma unroll
    for (int ks = 0; ks < 4; ks++) {
        bf16x8 af[4];
#pragma unroll
        for (int mt = 0; mt < 4; mt++)
            af[mt] = *reinterpret_cast<const bf16x8*>(
                ash + (mt * 16 + l15) * 136 + ks * 32 + lg * 8);
#pragma unroll
        for (int nn = 0; nn < 2; nn++) {
            int n = (wv * 2 + nn) * 16 + l15;
            bf16x8 bfr = *reinterpret_cast<const bf16x8*>(
                woB + (size_t)n * 128 + ks * 32 + lg * 8);
#pragma unroll
            for (int mt = 0; mt < 4; mt++)
                acc[mt][nn] = __builtin_amdgcn_mfma_f32_16x16x32_bf16(
                    af[mt], bfr, acc[mt][nn], 0, 0, 0);
        }
    }
    __syncthreads();
#pragma unroll
    for (int nn = 0; nn < 2; nn++) {
        int n = (wv * 2 + nn) * 16 + l15;
        float wb = wo_b[n];
#pragma unroll
        for (int mt = 0; mt < 4; mt++)
#pragma unroll
            for (int i = 0; i < 4; i++) {
                int r = mt * 16 + lg * 4 + i;
                float xb = bf2f(xbuf[(p0 + r) * 128 + n]);
                res[n * 68 + r] = acc[mt][nn][i] + wb + xb;
            }
    }
    __syncthreads();
    {
        int c = t >> 1, x0 = (t & 1) * 32;
        float* dst = out + ((size_t)(b * C + c) * 64 + y) * 64 + x0;
#pragma unroll
        for (int gblk = 0; gblk < 8; gblk++)
            *reinterpret_cast<float4*>(dst + gblk * 4) =
                *reinterpret_cast<const float4*>(&res[c * 68 + x0 + gblk * 4]);
    }
}

extern "C" void kernel_launch(void* const* d_in, const int* in_sizes, int n_in,
                              void* d_out, int out_size, void* d_ws, size_t ws_size,
                              hipStream_t stream) {
    const float* t1      = (const float*)d_in[0];
    const float* t2      = (const float*)d_in[1];
    const float* pos_w   = (const float*)d_in[2];
    const float* pos_b   = (const float*)d_in[3];
    const float* cat_w   = (const float*)d_in[4];
    const float* cat_b   = (const float*)d_in[5];
    const float* ln_cat_g= (const float*)d_in[6];
    const float* ln_cat_b= (const float*)d_in[7];
    const float* ln1_g   = (const float*)d_in[8];
    const float* ln1_b   = (const float*)d_in[9];
    const float* qkv_w   = (const float*)d_in[10];
    const float* qkv_b   = (const float*)d_in[11];
    const float* lepe_w  = (const float*)d_in[12];
    const float* lepe_b  = (const float*)d_in[13];
    const float* wo_w    = (const float*)d_in[14];
    const float* wo_b    = (const float*)d_in[15];

    float* ws    = (float*)d_ws;
    float* t1c   = ws + OFF_T1C;
    float* t2c   = ws + OFF_T2C;
    ushort_t* xbuf = (ushort_t*)(ws + OFF_X);
    ushort_t* qbuf = (ushort_t*)(ws + OFF_QB);
    ushort_t* kvbuf= (ushort_t*)(ws + OFF_KV);
    ushort_t* kb   = (ushort_t*)(ws + OFF_KVP);
    float* rw1   = ws + OFF_RW1;
    float* rw2   = ws + OFF_RW2;
    ushort_t* kvpT = (ushort_t*)(ws + OFF_KVPT);
    float* qwin  = ws + OFF_QW;
    float* kwin  = ws + OFF_KW;
    int*   ridx  = (int*)(ws + OFF_RIDX);
    ushort_t* wcat2 = (ushort_t*)(ws + OFF_WCB);
    ushort_t* qkvB  = (ushort_t*)(ws + OFF_QKVB);
    ushort_t* woB   = (ushort_t*)(ws + OFF_WOB);
    ushort_t* t1b   = (ushort_t*)(ws + OFF_T1B);
    ushort_t* t2b   = (ushort_t*)(ws + OFF_T2B);
    ushort_t* obuf  = (ushort_t*)(ws + OFF_T1C);  // alias t1c (dead after ln_qkv q)
    ushort_t* vpl   = (ushort_t*)(ws + OFF_T2C);  // alias t2c (dead after ln_qkv kv)
    ushort_t* lep   = (ushort_t*)(ws + OFF_KV);   // alias kvbuf (dead after pool_v)
    float* out   = (float*)d_out;

    transpose_weights<<<dim3((36 * 8 * 128 * 8 + 255) / 256), 256, 0, stream>>>(
        qkv_w, wo_w, cat_w, qkvB, woB, wcat2);
    pos_conv_k<<<dim3(2, 4, 256), 256, 0, stream>>>(
        t1, t2, pos_w, pos_b, t1c, t2c, t1b, t2b);
    catconv_mfma_k<<<dim3(8, 8, 8), 512, 0, stream>>>(
        t1b, t2b, wcat2, cat_b, ln_cat_g, ln_cat_b, xbuf);
    ln_qkv_both_k<<<dim3(512, 2), 256, 0, stream>>>(
        t1c, t2c, ln1_g, ln1_b, qkvB, qkv_b, qbuf, kvbuf, rw1, rw2);
    route_gemm_k<<<dim3(8, B), 256, 0, stream>>>(rw1, rw2, qkv_w, qkv_b, qwin, kwin);
    route_k<<<dim3(64, B), 64, 0, stream>>>(qwin, kwin, ridx);
    pool_v_k<<<dim3(64, B), 256, 0, stream>>>(kvbuf, kb, kvpT, vpl);
    attn_mfma_k<<<dim3(64, 4, B), 256, 0, stream>>>(qbuf, kb, kvpT, ridx, obuf);
    lepe_plane_k<<<dim3(C, B), 256, 0, stream>>>(vpl, lepe_w, lepe_b, lep);
    epilogue_mfma_k<<<dim3(512), 256, 0, stream>>>(obuf, lep, xbuf, woB, wo_b, out);
}

// Round 10
// 157.650 us; speedup vs baseline: 1.0651x; 1.0651x over previous
//
#include <hip/hip_runtime.h>
#include <math.h>

typedef unsigned short ushort_t;
typedef __attribute__((ext_vector_type(4))) float f32x4;
typedef __attribute__((ext_vector_type(16))) float f32x16;
typedef __attribute__((ext_vector_type(8))) short bf16x8;

constexpr int B = 8, C = 128, H = 64, W = 64;
constexpr int HEADS = 8, TOPK = 16;
constexpr int P2 = 64;
constexpr float SCALE = 0.0883883476483184405f; // 128^-0.5

// workspace offsets (in floats)
constexpr size_t NPIX    = (size_t)B * H * W;            // 32768
constexpr size_t OFF_T1C = 0;                            // NHWC fp32; later: o bf16
constexpr size_t OFF_T2C = OFF_T1C + NPIX * 128;         // NHWC fp32; later: v planes bf16
constexpr size_t OFF_X   = OFF_T2C + NPIX * 128;         // xbuf bf16 [pix][128]
constexpr size_t OFF_QB  = OFF_X   + NPIX * 128;         // q*SCALE bf16
constexpr size_t OFF_KV  = OFF_QB  + NPIX * 64;          // kv bf16 [pix][256]; later: lep planes bf16
constexpr size_t OFF_KVP = OFF_KV  + NPIX * 256;         // K bf16 [B,64,16,128]
constexpr size_t OFF_RW1 = OFF_KVP + 524288;             // rowsums q  [B][8][64][128] fp32
constexpr size_t OFF_RW2 = OFF_RW1 + 524288;             // rowsums kv [B][8][64][128] fp32
constexpr size_t OFF_KVPT= OFF_KVP + (size_t)B * P2 * 16 * 256; // v^T bf16 [B,64,128,16]
constexpr size_t OFF_QW  = OFF_KVPT+ (size_t)B * P2 * 128 * 16 / 2;
constexpr size_t OFF_KW  = OFF_QW  + (size_t)B * P2 * 128;
constexpr size_t OFF_RIDX= OFF_KW  + (size_t)B * P2 * 128;      // int
constexpr size_t OFF_WCB = OFF_RIDX+ (size_t)B * P2 * TOPK;     // wcat2 bf16 [36][2][4][128][8]
constexpr size_t OFF_QKVB= OFF_WCB + (size_t)9 * 256 * 128;     // qkv_w bf16 [384][128]
constexpr size_t OFF_WOB = OFF_QKVB+ (size_t)384 * 128 / 2;     // wo bf16 [128][128]
constexpr size_t OFF_T1B = OFF_WOB + 8192;               // t1 NHWC bf16 [pix][128]
constexpr size_t OFF_T2B = OFF_T1B + NPIX * 64;          // t2 NHWC bf16 [pix][128]

__device__ inline ushort_t f2bf(float f) {
    unsigned u = __float_as_uint(f);
    unsigned r = u + 0x7FFFu + ((u >> 16) & 1u);
    return (ushort_t)(r >> 16);
}
__device__ inline float bf2f(ushort_t u) {
    return __uint_as_float((unsigned)u << 16);
}

// ========== L1: weights prep (blocks 0..1151) || pos_conv (blocks 1152..3199)
__global__ __launch_bounds__(256) void prep_pos_k(
        const float* __restrict__ t1, const float* __restrict__ t2,
        const float* __restrict__ pos_w, const float* __restrict__ pos_b,
        const float* __restrict__ qkv_w, const float* __restrict__ wo_w,
        const float* __restrict__ cat_w,
        ushort_t* __restrict__ qkvB, ushort_t* __restrict__ woB,
        ushort_t* __restrict__ wcat2,
        float* __restrict__ out1, float* __restrict__ out2,
        ushort_t* __restrict__ ob1, ushort_t* __restrict__ ob2) {
    __shared__ float tile[4][32][33];
    int bid = blockIdx.x;
    int t = threadIdx.x;
    if (bid < 1152) {
        int idx = bid * 256 + t;
        if (idx < 384 * 128) qkvB[idx] = f2bf(qkv_w[idx]);   // [n][k]
        if (idx < 128 * 128) woB[idx]  = f2bf(wo_w[idx]);    // [n][k]
        if (idx < 36 * 8 * 128 * 8) {    // wcat2[((q*9+dd)*8+kk*4+lg)][n][i]
            int i  = idx & 7;
            int n  = (idx >> 3) & 127;
            int r  = idx >> 10;
            int lg = r & 3;
            int kk = (r >> 2) & 1;
            int sdd = r >> 3;
            int dd = sdd % 9, q = sdd / 9;
            int ci = q * 64 + kk * 32 + lg * 8 + i;
            wcat2[idx] = f2bf(cat_w[((size_t)n * 256 + ci) * 9 + dd]);
        }
        return;
    }
    int pb = bid - 1152;                 // 2048 blocks: (x:2, cg:4, z:256)
    int xb = pb & 1, cg = (pb >> 1) & 3, z = pb >> 3;
    int which = z >> 7, rem = z & 127;
    int b = rem >> 4, y0 = (rem & 15) * 4;
    const float* in = which ? t2 : t1;
    float* outNHWC = which ? out2 : out1;
    ushort_t* outB = which ? ob2 : ob1;
    int c0 = cg * 32, x0 = xb * 32;
    int tx = t & 31, tg = t >> 5;
    int x = x0 + tx;
    for (int i = 0; i < 4; i++) {
        int cl = tg * 4 + i, c = c0 + cl;
        const float* base = in + (size_t)(b * C + c) * H * W;
        float wv[9];
#pragma unroll
        for (int j = 0; j < 9; j++) wv[j] = pos_w[c * 9 + j];
        float rows[6][3];
#pragma unroll
        for (int yy = 0; yy < 6; yy++) {
            int gy = y0 - 1 + yy;
            bool yok = (gy >= 0 && gy < H);
#pragma unroll
            for (int dx = 0; dx < 3; dx++) {
                int gx = x + dx - 1;
                rows[yy][dx] = (yok && gx >= 0 && gx < W) ? base[gy * W + gx] : 0.f;
            }
        }
        float bb = pos_b[c];
#pragma unroll
        for (int k = 0; k < 4; k++) {
            float acc = rows[k + 1][1] + bb;   // residual (center) + bias
#pragma unroll
            for (int dy = 0; dy < 3; dy++)
#pragma unroll
                for (int dx = 0; dx < 3; dx++)
                    acc += rows[k + dy][dx] * wv[dy * 3 + dx];
            tile[k][cl][tx] = acc;
        }
    }
    __syncthreads();
    for (int k = 0; k < 4; k++)
        for (int i = 0; i < 4; i++) {
            int xl = tg * 4 + i;
            float val = tile[k][tx][xl];
            size_t idx = ((size_t)(b * H + y0 + k) * W + x0 + xl) * 128 + c0 + tx;
            outNHWC[idx] = val;
            outB[idx] = f2bf(val);
        }
}

// ========== L2: ln_qkv (blocks 0..511, 2 rows/block) || catconv (blocks 512..1023)
__global__ __launch_bounds__(512) void cat_ln_k(
        const ushort_t* __restrict__ t1b, const ushort_t* __restrict__ t2b,
        const ushort_t* __restrict__ wcat2,
        const float* __restrict__ cat_b,
        const float* __restrict__ gcat, const float* __restrict__ bcat,
        ushort_t* __restrict__ xbuf,
        const float* __restrict__ t1c, const float* __restrict__ t2c,
        const float* __restrict__ g1, const float* __restrict__ b1,
        const ushort_t* __restrict__ qkvB, const float* __restrict__ qkv_b,
        ushort_t* __restrict__ outQ, ushort_t* __restrict__ outKV,
        float* __restrict__ rw1, float* __restrict__ rw2) {
    __shared__ __align__(16) unsigned char smem[64 * 272 * 2]; // 34816 B, unioned
    int bid = blockIdx.x;
    int t = threadIdx.x;
    int lane = t & 63, wv = t >> 6;
    int l15 = lane & 15, lg = lane >> 4;

    if (bid < 512) {
        // ------------- ln_qkv role: 128 pixels (2 rows) per block -------------
        unsigned char* ash = smem;           // [128][272] bf16 rows
        int which = bid >> 8;                // 0: q from t1c, 1: kv from t2c
        int blk = bid & 255;
        const float* in = which ? t2c : t1c;
        float* rw = which ? rw2 : rw1;
        size_t p0 = (size_t)blk * 128;
        int bb_ = blk >> 5, y0 = (blk & 31) * 2;
        {
            int row = t >> 2, sub = t & 3;   // row in [0,128): (y-local, x)
            const float* src = in + (p0 + row) * 128 + sub * 32;
            float4 v[8];
            float s = 0.f;
#pragma unroll
            for (int j = 0; j < 8; j++) {
                v[j] = *reinterpret_cast<const float4*>(src + j * 4);
                s += v[j].x + v[j].y + v[j].z + v[j].w;
            }
            s += __shfl_xor(s, 1, 64); s += __shfl_xor(s, 2, 64);
            float mean = s * (1.f / 128.f);
            float s2 = 0.f;
#pragma unroll
            for (int j = 0; j < 8; j++) {
                float dx = v[j].x - mean, dy = v[j].y - mean;
                float dz = v[j].z - mean, dw = v[j].w - mean;
                s2 += dx * dx + dy * dy + dz * dz + dw * dw;
            }
            s2 += __shfl_xor(s2, 1, 64); s2 += __shfl_xor(s2, 2, 64);
            float inv = rsqrtf(s2 * (1.f / 128.f) + 1e-6f);
            int wj = (wv & 3) * 2 + (lane >> 5);
            int yy_ = y0 + (wv >> 2);
            bool writer = (lane & 28) == 0;
            float* rwp = rw + (((size_t)(bb_ * 8 + wj) * 64 + yy_) * 128) + sub * 32;
#pragma unroll
            for (int j = 0; j < 8; j++) {
                int c = sub * 32 + j * 4;
                float4 gv = *reinterpret_cast<const float4*>(g1 + c);
                float4 bv = *reinterpret_cast<const float4*>(b1 + c);
                float o0 = (v[j].x - mean) * inv * gv.x + bv.x;
                float o1 = (v[j].y - mean) * inv * gv.y + bv.y;
                float o2 = (v[j].z - mean) * inv * gv.z + bv.z;
                float o3 = (v[j].w - mean) * inv * gv.w + bv.w;
                uint2 pk;
                pk.x = (unsigned)f2bf(o0) | ((unsigned)f2bf(o1) << 16);
                pk.y = (unsigned)f2bf(o2) | ((unsigned)f2bf(o3) << 16);
                *reinterpret_cast<uint2*>(ash + row * 272 + c * 2) = pk;
                float r0 = o0, r1 = o1, r2 = o2, r3 = o3;
#pragma unroll
                for (int m = 4; m <= 16; m <<= 1) {
                    r0 += __shfl_xor(r0, m, 64);
                    r1 += __shfl_xor(r1, m, 64);
                    r2 += __shfl_xor(r2, m, 64);
                    r3 += __shfl_xor(r3, m, 64);
                }
                if (writer)
                    *reinterpret_cast<float4*>(rwp + j * 4) = make_float4(r0, r1, r2, r3);
            }
        }
        __syncthreads();
        int mh = wv >> 2, nw = wv & 3;     // m-half, n-group
        if (which == 0) {
            f32x4 acc[4][2];
#pragma unroll
            for (int mt = 0; mt < 4; mt++)
#pragma unroll
                for (int nn = 0; nn < 2; nn++)
                    acc[mt][nn] = (f32x4){0.f, 0.f, 0.f, 0.f};
#pragma unroll
            for (int ks = 0; ks < 4; ks++) {
                bf16x8 af[4];
#pragma unroll
                for (int mt = 0; mt < 4; mt++)
                    af[mt] = *reinterpret_cast<const bf16x8*>(
                        ash + (mh * 64 + mt * 16 + l15) * 272 + ks * 64 + lg * 16);
#pragma unroll
                for (int nn = 0; nn < 2; nn++) {
                    int n = (nw * 2 + nn) * 16 + l15;
                    bf16x8 bfr = *reinterpret_cast<const bf16x8*>(
                        qkvB + (size_t)n * 128 + ks * 32 + lg * 8);
#pragma unroll
                    for (int mt = 0; mt < 4; mt++)
                        acc[mt][nn] = __builtin_amdgcn_mfma_f32_16x16x32_bf16(
                            af[mt], bfr, acc[mt][nn], 0, 0, 0);
                }
            }
#pragma unroll
            for (int nn = 0; nn < 2; nn++) {
                int cg = (nw * 2 + nn) * 16 + l15;
                float bv = qkv_b[cg];
#pragma unroll
                for (int mt = 0; mt < 4; mt++)
#pragma unroll
                    for (int i = 0; i < 4; i++) {
                        size_t pix = p0 + mh * 64 + mt * 16 + lg * 4 + i;
                        outQ[pix * 128 + cg] = f2bf((acc[mt][nn][i] + bv) * SCALE);
                    }
            }
        } else {
            f32x4 acc[4][4];
#pragma unroll
            for (int mt = 0; mt < 4; mt++)
#pragma unroll
                for (int nn = 0; nn < 4; nn++)
                    acc[mt][nn] = (f32x4){0.f, 0.f, 0.f, 0.f};
#pragma unroll
            for (int ks = 0; ks < 4; ks++) {
                bf16x8 af[4];
#pragma unroll
                for (int mt = 0; mt < 4; mt++)
                    af[mt] = *reinterpret_cast<const bf16x8*>(
                        ash + (mh * 64 + mt * 16 + l15) * 272 + ks * 64 + lg * 16);
#pragma unroll
                for (int nn = 0; nn < 4; nn++) {
                    int n = 128 + (nw * 4 + nn) * 16 + l15;
                    bf16x8 bfr = *reinterpret_cast<const bf16x8*>(
                        qkvB + (size_t)n * 128 + ks * 32 + lg * 8);
#pragma unroll
                    for (int mt = 0; mt < 4; mt++)
                        acc[mt][nn] = __builtin_amdgcn_mfma_f32_16x16x32_bf16(
                            af[mt], bfr, acc[mt][nn], 0, 0, 0);
                }
            }
#pragma unroll
            for (int nn = 0; nn < 4; nn++) {
                int cg = (nw * 4 + nn) * 16 + l15;
                float bv = qkv_b[128 + cg];
#pragma unroll
                for (int mt = 0; mt < 4; mt++)
#pragma unroll
                    for (int i = 0; i < 4; i++) {
                        size_t pix = p0 + mh * 64 + mt * 16 + lg * 4 + i;
                        outKV[pix * 256 + cg] = f2bf(acc[mt][nn][i] + bv);
                    }
            }
        }
        return;
    }

    // ------------------------------ catconv role ------------------------------
    int cb = bid - 512;
    int mw = wv >> 2, nw = wv & 3;
    int b = cb >> 6, y0 = ((cb >> 3) & 7) * 8, x0 = (cb & 7) * 8;

    f32x4 acc[2][2];
#pragma unroll
    for (int m = 0; m < 2; m++)
#pragma unroll
        for (int cf = 0; cf < 2; cf++)
            acc[m][cf] = (f32x4){0.f, 0.f, 0.f, 0.f};

    int pyA[2], pxA[2];
#pragma unroll
    for (int m = 0; m < 2; m++) {
        int p = mw * 32 + m * 16 + l15;
        pyA[m] = p >> 3; pxA[m] = p & 7;
    }

    for (int q = 0; q < 4; q++) {
        __syncthreads();
        {
            const ushort_t* src = (q < 2 ? t1b : t2b);
            int coff = (q & 1) * 64;
            for (int e = t; e < 800; e += 512) {
                int pix = e >> 3, c8 = e & 7;
                int hy = pix / 10, hx = pix - hy * 10;
                int gy = y0 - 1 + hy, gx = x0 - 1 + hx;
                uint4 v = make_uint4(0u, 0u, 0u, 0u);
                if (gy >= 0 && gy < H && gx >= 0 && gx < W)
                    v = *reinterpret_cast<const uint4*>(
                        src + ((size_t)(b * H + gy) * W + gx) * 128 + coff + c8 * 8);
                *reinterpret_cast<uint4*>(smem + pix * 144 + c8 * 16) = v;
            }
        }
        __syncthreads();
#pragma unroll
        for (int dd = 0; dd < 9; dd++) {
            int dy = dd / 3, dx = dd - dy * 3;
            const ushort_t* wb = wcat2 + ((size_t)((q * 9 + dd) * 8 + lg) * 128) * 8;
            bf16x8 bfr[2][2];
#pragma unroll
            for (int kk = 0; kk < 2; kk++)
#pragma unroll
                for (int cf = 0; cf < 2; cf++)
                    bfr[kk][cf] = *reinterpret_cast<const bf16x8*>(
                        wb + (size_t)kk * 4096 + (nw * 32 + cf * 16 + l15) * 8);
            bf16x8 af[2][2];
#pragma unroll
            for (int m = 0; m < 2; m++)
#pragma unroll
                for (int kk = 0; kk < 2; kk++)
                    af[m][kk] = *reinterpret_cast<const bf16x8*>(
                        smem + ((pyA[m] + dy) * 10 + pxA[m] + dx) * 144 + kk * 64 + lg * 16);
#pragma unroll
            for (int m = 0; m < 2; m++)
#pragma unroll
                for (int cf = 0; cf < 2; cf++)
#pragma unroll
                    for (int kk = 0; kk < 2; kk++)
                        acc[m][cf] = __builtin_amdgcn_mfma_f32_16x16x32_bf16(
                            af[m][kk], bfr[kk][cf], acc[m][cf], 0, 0, 0);
        }
    }

    __syncthreads();
    float* res = (float*)smem;
    float* mstat = (float*)(smem + 64 * 132 * 4);
#pragma unroll
    for (int cf = 0; cf < 2; cf++) {
        int n = nw * 32 + cf * 16 + l15;
        float cbv = cat_b[n];
#pragma unroll
        for (int m = 0; m < 2; m++)
#pragma unroll
            for (int i = 0; i < 4; i++)
                res[(mw * 32 + m * 16 + lg * 4 + i) * 132 + n] = acc[m][cf][i] + cbv;
    }
    __syncthreads();
    {
        int pix = t >> 3, sub = t & 7;
        float s1 = 0.f;
#pragma unroll
        for (int j = 0; j < 16; j++) s1 += res[pix * 132 + sub + j * 8];
        s1 += __shfl_xor(s1, 1, 64);
        s1 += __shfl_xor(s1, 2, 64);
        s1 += __shfl_xor(s1, 4, 64);
        float mean = s1 * (1.f / 128.f);
        float s2 = 0.f;
#pragma unroll
        for (int j = 0; j < 16; j++) {
            float d = res[pix * 132 + sub + j * 8] - mean;
            s2 += d * d;
        }
        s2 += __shfl_xor(s2, 1, 64);
        s2 += __shfl_xor(s2, 2, 64);
        s2 += __shfl_xor(s2, 4, 64);
        float inv = rsqrtf(s2 * (1.f / 128.f) + 1e-5f);
        if (sub == 0) { mstat[pix] = mean; mstat[64 + pix] = inv; }
    }
    __syncthreads();
    {
        int c = t & 127, pg = t >> 7;
        float gg = gcat[c], bb = bcat[c];
        for (int j = 0; j < 16; j++) {
            int p2 = j * 4 + pg;
            float v = (res[p2 * 132 + c] - mstat[p2]) * mstat[64 + p2] * gg + bb;
            int py = p2 >> 3, px = p2 & 7;
            xbuf[((size_t)(b * H + y0 + py) * W + x0 + px) * 128 + c] = f2bf(fmaxf(v, 0.f));
        }
    }
}

// ========== L3: route_gemm (blocks 0..63) || pool_v (blocks 64..575)
__global__ __launch_bounds__(256) void route_pool_k(
        const float* __restrict__ rw1, const float* __restrict__ rw2,
        const float* __restrict__ qkv_w, const float* __restrict__ qkv_b,
        float* __restrict__ qwin, float* __restrict__ kwin,
        const ushort_t* __restrict__ kv,
        ushort_t* __restrict__ kb, ushort_t* __restrict__ kvpT,
        ushort_t* __restrict__ vpl) {
    __shared__ float msh[2][8][128];
    int bid = blockIdx.x;
    int t = threadIdx.x;
    if (bid < 64) {
        int b = bid >> 3, wi = bid & 7;
        for (int i = t; i < 8 * 128; i += 256) {
            int r = i >> 7, c = i & 127;
            size_t off = (((size_t)(b * 8 + r) * 64) + wi * 8) * 128 + c;
            float s1 = 0.f, s2 = 0.f;
#pragma unroll
            for (int rr = 0; rr < 8; rr++) {
                s1 += rw1[off + rr * 128];
                s2 += rw2[off + rr * 128];
            }
            msh[0][r][c] = s1 * (1.f / 64.f);
            msh[1][r][c] = s2 * (1.f / 64.f);
        }
        __syncthreads();
        int c = t;
        int which = c >> 7;
        const float* wrow = qkv_w + (size_t)c * 128;
        float acc[8];
#pragma unroll
        for (int r = 0; r < 8; r++) acc[r] = 0.f;
        for (int k = 0; k < 128; k++) {
            float wv_ = wrow[k];
#pragma unroll
            for (int r = 0; r < 8; r++) acc[r] += msh[which][r][k] * wv_;
        }
        float bv = qkv_b[c];
#pragma unroll
        for (int r = 0; r < 8; r++) {
            size_t o = ((size_t)b * 64 + wi * 8 + r) * 128 + (c & 127);
            (which ? kwin : qwin)[o] = acc[r] + bv;
        }
        return;
    }
    int pb = bid - 64;
    int b = pb >> 6, wdw = pb & 63;
    int wi = wdw >> 3, wj = wdw & 7;
    if (t < 128) {
        float vals[16];
        for (int ry = 0; ry < 4; ry++)
            for (int rx = 0; rx < 4; rx++) {
                float s = 0.f;
                for (int fy = 0; fy < 2; fy++)
                    for (int fx = 0; fx < 2; fx++) {
                        int y = wi * 8 + ry * 2 + fy, x = wj * 8 + rx * 2 + fx;
                        s += bf2f(kv[((size_t)(b * H + y) * W + x) * 256 + t]);
                    }
                vals[ry * 4 + rx] = s * 0.25f;
            }
#pragma unroll
        for (int pos = 0; pos < 16; pos++)
            kb[(((size_t)(b * 64 + wdw)) * 16 + pos) * 128 + t] = f2bf(vals[pos]);
    } else {
        int c = t - 128;
        float ps[4][4];
#pragma unroll
        for (int i = 0; i < 4; i++)
#pragma unroll
            for (int j = 0; j < 4; j++) ps[i][j] = 0.f;
        for (int y = 0; y < 8; y++) {
            union { ushort_t u16[8]; uint4 u4; } raw;
#pragma unroll
            for (int x = 0; x < 8; x++) {
                raw.u16[x] = kv[((size_t)(b * H + wi * 8 + y) * W + wj * 8 + x) * 256 + 128 + c];
                ps[y >> 1][x >> 1] += bf2f(raw.u16[x]);
            }
            *reinterpret_cast<uint4*>(
                vpl + ((size_t)(b * C + c) * H + wi * 8 + y) * W + wj * 8) = raw.u4;
        }
        union { ushort_t u16[16]; uint4 u4[2]; } pk;
#pragma unroll
        for (int ry = 0; ry < 4; ry++)
#pragma unroll
            for (int rx = 0; rx < 4; rx++)
                pk.u16[ry * 4 + rx] = f2bf(ps[ry][rx] * 0.25f);
        size_t base = (((size_t)(b * 64 + wdw)) * 128 + c) * 16;
        *reinterpret_cast<uint4*>(kvpT + base) = pk.u4[0];
        *reinterpret_cast<uint4*>(kvpT + base + 8) = pk.u4[1];
    }
}

// ========== L4: route_k 4-win/block (blocks 0..127) || lepe (blocks 128..1151)
__global__ __launch_bounds__(256) void route_lepe_k(
        const float* __restrict__ q_win, const float* __restrict__ k_win,
        int* __restrict__ r_idx,
        const ushort_t* __restrict__ vpl,
        const float* __restrict__ w, const float* __restrict__ bias,
        ushort_t* __restrict__ lep) {
    __shared__ float tile[68][69];
    int bid = blockIdx.x;
    int t = threadIdx.x;
    if (bid < 128) {
        int b = bid >> 4, p = (bid & 15) * 4 + (t >> 6);
        int j = t & 63;
        const float* qp = q_win + (size_t)(b * 64 + p) * 128;
        const float* kp = k_win + (size_t)(b * 64 + j) * 128;
        float lg = 0.f;
        for (int c = 0; c < 128; c++) lg += qp[c] * kp[c];
        lg *= SCALE;
        for (int it = 0; it < TOPK; it++) {
            float v = lg; int idx = j;
#pragma unroll
            for (int m = 32; m > 0; m >>= 1) {
                float ov = __shfl_xor(v, m, 64);
                int   oi = __shfl_xor(idx, m, 64);
                if (ov > v || (ov == v && oi < idx)) { v = ov; idx = oi; }
            }
            if (j == 0) r_idx[(size_t)(b * 64 + p) * TOPK + it] = idx;
            if (j == idx) lg = -__builtin_inff();
        }
        return;
    }
    int lb = bid - 128;
    int c = lb & 127, b = lb >> 7;
    const ushort_t* plane = vpl + (size_t)(b * C + c) * 4096;
    for (int e = t; e < 68 * 68; e += 256) {
        int row = e / 68, col = e - row * 68;
        int gy = row - 2, gx = col - 2;
        tile[row][col] = (gy >= 0 && gy < 64 && gx >= 0 && gx < 64)
                         ? bf2f(plane[gy * 64 + gx]) : 0.f;
    }
    float wv[25];
#pragma unroll
    for (int j = 0; j < 25; j++) wv[j] = w[c * 25 + j];
    float bb = bias[c];
    __syncthreads();
    int y = t >> 2, x0 = (t & 3) * 16;
    float acc[16];
#pragma unroll
    for (int i = 0; i < 16; i++) acc[i] = bb;
#pragma unroll
    for (int dy = 0; dy < 5; dy++) {
        float vals[20];
#pragma unroll
        for (int j = 0; j < 20; j++) vals[j] = tile[y + dy][x0 + j];
#pragma unroll
        for (int dx = 0; dx < 5; dx++)
#pragma unroll
            for (int i = 0; i < 16; i++)
                acc[i] += vals[i + dx] * wv[dy * 5 + dx];
    }
    ushort_t* dst = lep + (size_t)(b * C + c) * 4096 + y * 64 + x0;
    union { ushort_t u16[16]; uint4 u4[2]; } pk;
#pragma unroll
    for (int i = 0; i < 16; i++) pk.u16[i] = f2bf(acc[i]);
    *reinterpret_cast<uint4*>(dst) = pk.u4[0];
    *reinterpret_cast<uint4*>(dst + 8) = pk.u4[1];
}

// ========== L5: routed attention (unchanged)
__global__ __launch_bounds__(256) void attn_mfma_k(
        const ushort_t* __restrict__ qb,     // bf16 q*SCALE [B,H,W,128]
        const ushort_t* __restrict__ kb,     // bf16 [B,64,16,128]
        const ushort_t* __restrict__ kvpT,   // bf16 [B,64,128,16]
        const int* __restrict__ r_idx,
        ushort_t* __restrict__ o) {          // bf16 [pix][128]
    __shared__ int ridx_sh[16];
    __shared__ float denom_sh[4][32];
    __shared__ __align__(16) ushort_t osh[64][32];

    int b = blockIdx.z, p = blockIdx.x, pair = blockIdx.y;
    int wi = p >> 3, wj = p & 7;
    int t = threadIdx.x;
    int lane = t & 63, wv = t >> 6;
    int l31 = lane & 31, hi = lane >> 5;

    if (t < 16) ridx_sh[t] = r_idx[(size_t)(b * 64 + p) * TOPK + t];
    __syncthreads();

    int hh = wv >> 1, qt = wv & 1;
    int h = pair * 2 + hh;

    int q = qt * 32 + l31;
    int qy = wi * 8 + (q >> 3), qx = wj * 8 + (q & 7);
    bf16x8 qf = *reinterpret_cast<const bf16x8*>(
        qb + ((size_t)(b * H + qy) * W + qx) * 128 + h * 16 + hi * 8);

    const ushort_t* kb_b = kb + (size_t)b * 64 * 16 * 128 + h * 16 + hi * 8;
    const ushort_t* vt_b = kvpT + (size_t)b * 64 * 128 * 16 + (h * 16 + (l31 & 15)) * 16 + hi * 8;

    float m_run = -INFINITY, l_run = 0.f;
    f32x16 opv;
#pragma unroll
    for (int r = 0; r < 16; r++) opv[r] = 0.f;
    f32x16 zf;
#pragma unroll
    for (int r = 0; r < 16; r++) zf[r] = 0.f;

    bf16x8 kf = *reinterpret_cast<const bf16x8*>(
        kb_b + ((size_t)ridx_sh[l31 >> 4] * 16 + (l31 & 15)) * 128);
    bf16x8 v0 = *reinterpret_cast<const bf16x8*>(vt_b + (size_t)ridx_sh[0] * 2048);
    bf16x8 v1 = *reinterpret_cast<const bf16x8*>(vt_b + (size_t)ridx_sh[1] * 2048);

    for (int t8 = 0; t8 < 8; t8++) {
        bf16x8 kfn = kf, v0n = v0, v1n = v1;
        if (t8 < 7) {
            kfn = *reinterpret_cast<const bf16x8*>(
                kb_b + ((size_t)ridx_sh[2 * t8 + 2 + (l31 >> 4)] * 16 + (l31 & 15)) * 128);
            v0n = *reinterpret_cast<const bf16x8*>(vt_b + (size_t)ridx_sh[2 * t8 + 2] * 2048);
            v1n = *reinterpret_cast<const bf16x8*>(vt_b + (size_t)ridx_sh[2 * t8 + 3] * 2048);
        }
        f32x16 S = __builtin_amdgcn_mfma_f32_32x32x16_bf16(kf, qf, zf, 0, 0, 0);
        float tm = S[0];
#pragma unroll
        for (int r = 1; r < 16; r++) tm = fmaxf(tm, S[r]);
        tm = fmaxf(tm, __shfl_xor(tm, 32, 64));
        float m_new = fmaxf(m_run, tm);
        float corr = __expf(m_run - m_new);
        float p_[16], psum = 0.f;
#pragma unroll
        for (int r = 0; r < 16; r++) { p_[r] = __expf(S[r] - m_new); psum += p_[r]; }
        psum += __shfl_xor(psum, 32, 64);
        l_run = l_run * corr + psum;
        m_run = m_new;
#pragma unroll
        for (int r = 0; r < 16; r++) opv[r] *= corr;
        unsigned w_[8], pw_[8];
#pragma unroll
        for (int j = 0; j < 8; j++)
            w_[j] = (__float_as_uint(p_[2 * j]) >> 16) |
                    (__float_as_uint(p_[2 * j + 1]) & 0xFFFF0000u);
#pragma unroll
        for (int j = 0; j < 8; j++) pw_[j] = __shfl_xor(w_[j], 32, 64);
        union { unsigned u[4]; bf16x8 v; } fa0, fa1;
        fa0.u[0] = hi ? pw_[2] : w_[0];
        fa0.u[1] = hi ? pw_[3] : w_[1];
        fa0.u[2] = hi ? w_[2]  : pw_[0];
        fa0.u[3] = hi ? w_[3]  : pw_[1];
        fa1.u[0] = hi ? pw_[6] : w_[4];
        fa1.u[1] = hi ? pw_[7] : w_[5];
        fa1.u[2] = hi ? w_[6]  : pw_[4];
        fa1.u[3] = hi ? w_[7]  : pw_[5];
        opv = __builtin_amdgcn_mfma_f32_32x32x16_bf16(fa0.v, v0, opv, 0, 0, 0);
        opv = __builtin_amdgcn_mfma_f32_32x32x16_bf16(fa1.v, v1, opv, 0, 0, 0);
        kf = kfn; v0 = v0n; v1 = v1n;
    }
    denom_sh[wv][l31] = l_run;
    if (l31 < 16) {
#pragma unroll
        for (int r = 0; r < 16; r++) {
            int qr = (r & 3) + 8 * (r >> 2) + 4 * hi;
            float invd = 1.f / denom_sh[wv][qr];
            osh[qt * 32 + qr][hh * 16 + l31] = f2bf(opv[r] * invd);
        }
    }
    __syncthreads();
    {
        int p_ = t >> 2, seg = t & 3;
        int y = wi * 8 + (p_ >> 3), x = wj * 8 + (p_ & 7);
        *reinterpret_cast<uint4*>(
            o + ((size_t)(b * H + y) * W + x) * 128 + pair * 32 + seg * 8) =
            *reinterpret_cast<const uint4*>(&osh[p_][seg * 8]);
    }
}

// ========== L6: epilogue (unchanged)
__global__ __launch_bounds__(256) void epilogue_mfma_k(
        const ushort_t* __restrict__ o,      // bf16 [pix][128]
        const ushort_t* __restrict__ lep,    // bf16 planes [B][C][64][64]
        const ushort_t* __restrict__ xbuf,   // bf16 [pix][128]
        const ushort_t* __restrict__ woB,    // bf16 [128][128]
        const float* __restrict__ wo_b,
        float* __restrict__ out) {
    __shared__ __align__(16) unsigned char smem[128 * 68 * 4]; // 34816 B
    ushort_t* ash = (ushort_t*)smem;         // [64][136] bf16 (o+lep)
    float* res = (float*)smem;               // [128][68] fp32 (after MFMA)
    int t = threadIdx.x, lane = t & 63, wv = t >> 6;
    int bid = blockIdx.x;
    int b = bid >> 6, y = bid & 63;
    size_t p0 = (size_t)bid * 64;

#pragma unroll
    for (int k = 0; k < 4; k++) {
        int e = k * 256 + t;
        int c = e >> 3, xg = e & 7;
        union { uint4 u4; ushort_t u16[8]; } v;
        v.u4 = *reinterpret_cast<const uint4*>(
            lep + (((size_t)(b * C + c) * 64 + y) * 64) + xg * 8);
#pragma unroll
        for (int j = 0; j < 8; j++) ash[(xg * 8 + j) * 136 + c] = v.u16[j];
    }
    __syncthreads();
    {
        int x = t >> 2, sub = t & 3;
        const ushort_t* op = o + (p0 + x) * 128 + sub * 32;
        ushort_t* ap = ash + x * 136 + sub * 32;
#pragma unroll
        for (int jj = 0; jj < 4; jj++) {
            union { uint4 u4; ushort_t u16[8]; } ov, lv;
            ov.u4 = *reinterpret_cast<const uint4*>(op + jj * 8);
            lv.u4 = *reinterpret_cast<const uint4*>(ap + jj * 8);
#pragma unroll
            for (int j = 0; j < 8; j++)
                lv.u16[j] = f2bf(bf2f(ov.u16[j]) + bf2f(lv.u16[j]));
            *reinterpret_cast<uint4*>(ap + jj * 8) = lv.u4;
        }
    }
    __syncthreads();
    int l15 = lane & 15, lg = lane >> 4;
    f32x4 acc[4][2];
#pragma unroll
    for (int mt = 0; mt < 4; mt++)
#pragma unroll
        for (int nn = 0; nn < 2; nn++)
            acc[mt][nn] = (f32x4){0.f, 0.f, 0.f, 0.f};
#pragma unroll
    for (int ks = 0; ks < 4; ks++) {
        bf16x8 af[4];
#pragma unroll
        for (int mt = 0; mt < 4; mt++)
            af[mt] = *reinterpret_cast<const bf16x8*>(
                ash + (mt * 16 + l15) * 136 + ks * 32 + lg * 8);
#pragma unroll
        for (int nn = 0; nn < 2; nn++) {
            int n = (wv * 2 + nn) * 16 + l15;
            bf16x8 bfr = *reinterpret_cast<const bf16x8*>(
                woB + (size_t)n * 128 + ks * 32 + lg * 8);
#pragma unroll
            for (int mt = 0; mt < 4; mt++)
                acc[mt][nn] = __builtin_amdgcn_mfma_f32_16x16x32_bf16(
                    af[mt], bfr, acc[mt][nn], 0, 0, 0);
        }
    }
    __syncthreads();
#pragma unroll
    for (int nn = 0; nn < 2; nn++) {
        int n = (wv * 2 + nn) * 16 + l15;
        float wb = wo_b[n];
#pragma unroll
        for (int mt = 0; mt < 4; mt++)
#pragma unroll
            for (int i = 0; i < 4; i++) {
                int r = mt * 16 + lg * 4 + i;
                float xb = bf2f(xbuf[(p0 + r) * 128 + n]);
                res[n * 68 + r] = acc[mt][nn][i] + wb + xb;
            }
    }
    __syncthreads();
    {
        int c = t >> 1, x0 = (t & 1) * 32;
        float* dst = out + ((size_t)(b * C + c) * 64 + y) * 64 + x0;
#pragma unroll
        for (int gblk = 0; gblk < 8; gblk++)
            *reinterpret_cast<float4*>(dst + gblk * 4) =
                *reinterpret_cast<const float4*>(&res[c * 68 + x0 + gblk * 4]);
    }
}

extern "C" void kernel_launch(void* const* d_in, const int* in_sizes, int n_in,
                              void* d_out, int out_size, void* d_ws, size_t ws_size,
                              hipStream_t stream) {
    const float* t1      = (const float*)d_in[0];
    const float* t2      = (const float*)d_in[1];
    const float* pos_w   = (const float*)d_in[2];
    const float* pos_b   = (const float*)d_in[3];
    const float* cat_w   = (const float*)d_in[4];
    const float* cat_b   = (const float*)d_in[5];
    const float* ln_cat_g= (const float*)d_in[6];
    const float* ln_cat_b= (const float*)d_in[7];
    const float* ln1_g   = (const float*)d_in[8];
    const float* ln1_b   = (const float*)d_in[9];
    const float* qkv_w   = (const float*)d_in[10];
    const float* qkv_b   = (const float*)d_in[11];
    const float* lepe_w  = (const float*)d_in[12];
    const float* lepe_b  = (const float*)d_in[13];
    const float* wo_w    = (const float*)d_in[14];
    const float* wo_b    = (const float*)d_in[15];

    float* ws    = (float*)d_ws;
    float* t1c   = ws + OFF_T1C;
    float* t2c   = ws + OFF_T2C;
    ushort_t* xbuf = (ushort_t*)(ws + OFF_X);
    ushort_t* qbuf = (ushort_t*)(ws + OFF_QB);
    ushort_t* kvbuf= (ushort_t*)(ws + OFF_KV);
    ushort_t* kb   = (ushort_t*)(ws + OFF_KVP);
    float* rw1   = ws + OFF_RW1;
    float* rw2   = ws + OFF_RW2;
    ushort_t* kvpT = (ushort_t*)(ws + OFF_KVPT);
    float* qwin  = ws + OFF_QW;
    float* kwin  = ws + OFF_KW;
    int*   ridx  = (int*)(ws + OFF_RIDX);
    ushort_t* wcat2 = (ushort_t*)(ws + OFF_WCB);
    ushort_t* qkvB  = (ushort_t*)(ws + OFF_QKVB);
    ushort_t* woB   = (ushort_t*)(ws + OFF_WOB);
    ushort_t* t1b   = (ushort_t*)(ws + OFF_T1B);
    ushort_t* t2b   = (ushort_t*)(ws + OFF_T2B);
    ushort_t* obuf  = (ushort_t*)(ws + OFF_T1C);  // alias t1c (dead after cat_ln)
    ushort_t* vpl   = (ushort_t*)(ws + OFF_T2C);  // alias t2c (dead after cat_ln)
    ushort_t* lep   = (ushort_t*)(ws + OFF_KV);   // alias kvbuf (dead after route_pool)
    float* out   = (float*)d_out;

    prep_pos_k<<<3200, 256, 0, stream>>>(
        t1, t2, pos_w, pos_b, qkv_w, wo_w, cat_w,
        qkvB, woB, wcat2, t1c, t2c, t1b, t2b);
    cat_ln_k<<<1024, 512, 0, stream>>>(
        t1b, t2b, wcat2, cat_b, ln_cat_g, ln_cat_b, xbuf,
        t1c, t2c, ln1_g, ln1_b, qkvB, qkv_b, qbuf, kvbuf, rw1, rw2);
    route_pool_k<<<576, 256, 0, stream>>>(
        rw1, rw2, qkv_w, qkv_b, qwin, kwin, kvbuf, kb, kvpT, vpl);
    route_lepe_k<<<1152, 256, 0, stream>>>(
        qwin, kwin, ridx, vpl, lepe_w, lepe_b, lep);
    attn_mfma_k<<<dim3(64, 4, B), 256, 0, stream>>>(qbuf, kb, kvpT, ridx, obuf);
    epilogue_mfma_k<<<512, 256, 0, stream>>>(obuf, lep, xbuf, woB, wo_b, out);
}